// Round 11
// baseline (299.914 us; speedup 1.0000x reference)
//
#include <hip/hip_runtime.h>
#include <hip/hip_bf16.h>

#define DIMC 384
#define NHEADS 8
#define HDIM 48
#define OFFD 96
#define NPIX 1024
#define BB 8

typedef short bf16s;  // bf16 bits in short
typedef __attribute__((ext_vector_type(8))) short short8;
typedef __attribute__((ext_vector_type(4))) float f32x4;

__device__ __forceinline__ short f2b(float f) {
  union { float f; unsigned u; } v; v.f = f;
  unsigned r = (v.u + 0x7fffu + ((v.u >> 16) & 1u)) >> 16;
  return (short)r;
}
__device__ __forceinline__ float b2f(short s) {
  union { unsigned u; float f; } v; v.u = ((unsigned)(unsigned short)s) << 16; return v.f;
}
__device__ __forceinline__ unsigned pk2(float a, float b) {
  union { __hip_bfloat162 h; unsigned u; } v;
  v.h = __float22bfloat162_rn(float2{a, b});
  return v.u;
}

// ---------------- weight prep: Wq -> hi/lo bf16x2 ; Wk/Wv/Wp -> bf16 ----------------
__global__ __launch_bounds__(256) void prep_weights(
    const float* __restrict__ Wq, const float* __restrict__ Wk,
    const float* __restrict__ Wv, const float* __restrict__ Wp,
    bf16s* __restrict__ wqh, bf16s* __restrict__ wql,
    bf16s* __restrict__ wkb, bf16s* __restrict__ wvb, bf16s* __restrict__ wpb) {
  int idx = blockIdx.x * 256 + threadIdx.x;
  if (idx >= 4 * 147456) return;
  int which = idx / 147456, e = idx % 147456;
  if (which == 0) {
    float v = Wq[e]; short h = f2b(v);
    wqh[e] = h; wql[e] = f2b(v - b2f(h));
  } else if (which == 1) wkb[e] = f2b(Wk[e]);
  else if (which == 2) wvb[e] = f2b(Wv[e]);
  else wpb[e] = f2b(Wp[e]);
}

// ---------------- x (B,C,NPIX) fp32 -> x_hi/x_lo bf16 [m=8192][k=384] ----------------
__global__ __launch_bounds__(256) void transpose_split(const float* __restrict__ x,
    bf16s* __restrict__ xh, bf16s* __restrict__ xl) {
  __shared__ float ts[64][65];
  int np0 = blockIdx.x * 64, c0 = blockIdx.y * 64, b = blockIdx.z;
  int t = threadIdx.x;
  int a = t & 63, bq = t >> 6;
#pragma unroll
  for (int i = 0; i < 16; ++i) {
    int cl = bq + i * 4;
    ts[cl][a] = x[((size_t)(b * DIMC + c0 + cl)) * NPIX + np0 + a];
  }
  __syncthreads();
#pragma unroll
  for (int i = 0; i < 16; ++i) {
    int npl = bq + i * 4;
    float v = ts[a][npl];
    short h = f2b(v);
    size_t o = ((size_t)(b * NPIX + np0 + npl)) * DIMC + c0 + a;
    xh[o] = h; xl[o] = f2b(v - b2f(h));
  }
}

// ---------------- LDS-staged MFMA GEMM ----------------
// MODE 0: Q bf16x3 (A=xh/xl, W=wqh/wql)  -> qg fp32 planar + qbuf bf16 [bh][n][64pad]
// MODE 1: KV fused (A=kvf, W=wk/wv)      -> K [bh][n][64pad], V [bh][d][n]
// MODE 2: proj     (A=attnout, W=wp)     -> fp32 NCHW + bias
template<int MODE>
__global__ __launch_bounds__(256) void gemm_lds(
    const bf16s* __restrict__ Ah, const bf16s* __restrict__ Al,
    const bf16s* __restrict__ Wa, const bf16s* __restrict__ Wb,
    float* __restrict__ outF, bf16s* __restrict__ outB, bf16s* __restrict__ outB2,
    const float* __restrict__ bias) {
  __shared__ __align__(16) short wlds[25600];  // 50 KB -> 3 blocks/CU
  const int NS  = (MODE == 2) ? 1 : 2;
  const int KCN = (MODE == 2) ? 48 : 24;
  const int STR = (MODE == 2) ? 392 : 200;
  int t = threadIdx.x;
  int w = t >> 6, lane = t & 63, quad = lane >> 4, l16 = lane & 15;
  int n0 = blockIdx.x * 64;
  int m0 = blockIdx.y * 64 + w * 16;
  f32x4 acc[4], acc2[4];
#pragma unroll
  for (int nt = 0; nt < 4; ++nt) {
    acc[nt] = (f32x4){0.f, 0.f, 0.f, 0.f};
    if (MODE != 2) acc2[nt] = (f32x4){0.f, 0.f, 0.f, 0.f};
  }
  const bf16s* arow_a = Ah + (size_t)(m0 + l16) * DIMC;
  const bf16s* arow_l = (MODE == 0) ? (Al + (size_t)(m0 + l16) * DIMC) : nullptr;

  for (int s = 0; s < NS; ++s) {
    if (s) __syncthreads();
    int kcb = s * 24;
#pragma unroll
    for (int ii = 0; ii < (KCN * 64) / 256; ++ii) {
      int i = ii * 256 + t;
      int n = i / KCN, kcl = i % KCN;
      *(short8*)(&wlds[n * STR + kcl * 8]) =
          *(const short8*)(Wa + (size_t)(n0 + n) * DIMC + (kcb + kcl) * 8);
      if (MODE != 2)
        *(short8*)(&wlds[12800 + n * STR + kcl * 8]) =
            *(const short8*)(Wb + (size_t)(n0 + n) * DIMC + (kcb + kcl) * 8);
    }
    __syncthreads();
    int k0beg = s * 6, k0cnt = (MODE == 2) ? 12 : 6;
#pragma unroll
    for (int kk = 0; kk < k0cnt; ++kk) {
      int k0 = k0beg + kk;
      short8 a0 = *(const short8*)(arow_a + k0 * 32 + quad * 8);
      short8 a1;
      if (MODE == 0) a1 = *(const short8*)(arow_l + k0 * 32 + quad * 8);
      int kcl = kk * 4 + quad;
#pragma unroll
      for (int nt = 0; nt < 4; ++nt) {
        int n = nt * 16 + l16;
        short8 b0 = *(const short8*)(&wlds[n * STR + kcl * 8]);
        acc[nt] = __builtin_amdgcn_mfma_f32_16x16x32_bf16(a0, b0, acc[nt], 0, 0, 0);
        if (MODE == 0) {
          short8 b1 = *(const short8*)(&wlds[12800 + n * STR + kcl * 8]);
          acc[nt] = __builtin_amdgcn_mfma_f32_16x16x32_bf16(a1, b0, acc[nt], 0, 0, 0);
          acc[nt] = __builtin_amdgcn_mfma_f32_16x16x32_bf16(a0, b1, acc[nt], 0, 0, 0);
        } else if (MODE == 1) {
          short8 b1 = *(const short8*)(&wlds[12800 + n * STR + kcl * 8]);
          acc2[nt] = __builtin_amdgcn_mfma_f32_16x16x32_bf16(a0, b1, acc2[nt], 0, 0, 0);
        }
      }
    }
  }
#pragma unroll
  for (int nt = 0; nt < 4; ++nt) {
    int c = n0 + nt * 16 + l16;
#pragma unroll
    for (int r = 0; r < 4; ++r) {
      int m = m0 + quad * 4 + r;
      int b = m >> 10, np = m & 1023;
      float v = acc[nt][r];
      if (MODE == 0) {
        int g = c / OFFD, cc = c % OFFD;
        outF[((size_t)((b * 4 + g) * OFFD + cc)) * NPIX + np] = v;
        int h = c / HDIM, d = c % HDIM;
        outB[((size_t)((b * 8 + h) * NPIX + np)) * 64 + d] = f2b(v);
      } else if (MODE == 1) {
        int h = c / HDIM, d = c % HDIM;
        outB[((size_t)((b * 8 + h) * NPIX + np)) * 64 + d] = f2b(v);
        outB2[((size_t)((b * 8 + h) * HDIM + d)) * NPIX + np] = f2b(acc2[nt][r]);
      } else {
        outF[((size_t)(b * DIMC + c)) * NPIX + np] = v + bias[c];
      }
    }
  }
}

// ---------------- offset convs: register-tiled, 2 channels per barrier ----------------
__global__ __launch_bounds__(256) void conv_off_part(const float* __restrict__ qg,
    const float* __restrict__ W1, const float* __restrict__ W2, float* __restrict__ pbuf) {
  __shared__ float ts[2][42 * 43];
  int chunk = blockIdx.x & 15, bg = blockIdx.x >> 4;
  int t = threadIdx.x;
  int y = t >> 3, x0 = (t & 7) * 4;
  float a0[4] = {0.f, 0.f, 0.f, 0.f}, a1[4] = {0.f, 0.f, 0.f, 0.f};
  const float* plane0 = qg + (size_t)bg * OFFD * NPIX;
  for (int ci2 = 0; ci2 < 3; ++ci2) {
    int ccb = chunk * 6 + ci2 * 2;
    __syncthreads();
    for (int e = t; e < 2 * 42 * 42; e += 256) {
      int u = e >= 42 * 42;
      int e2 = e - u * 42 * 42;
      int r = e2 / 42, c = e2 - r * 42;
      int gy = r - 5, gx = c - 5;
      const float* plane = plane0 + (size_t)(ccb + u) * NPIX;
      ts[u][r * 43 + c] = (gy >= 0 && gy < 32 && gx >= 0 && gx < 32) ? plane[gy * 32 + gx] : 0.f;
    }
    __syncthreads();
#pragma unroll
    for (int u = 0; u < 2; ++u) {
      int cc = ccb + u;
      const float* w1c0 = W1 + (size_t)cc * 25;
      const float* w1c1 = W1 + (size_t)(OFFD + cc) * 25;
      const float* w2c0 = W2 + (size_t)cc * 121;
      const float* w2c1 = W2 + (size_t)(OFFD + cc) * 121;
#pragma unroll
      for (int ky = 0; ky < 11; ++ky) {
        float rv[14];
#pragma unroll
        for (int j = 0; j < 14; ++j) rv[j] = ts[u][(y + ky) * 43 + x0 + j];
#pragma unroll
        for (int kx = 0; kx < 11; ++kx) {
          float w0 = w2c0[ky * 11 + kx], w1v = w2c1[ky * 11 + kx];
#pragma unroll
          for (int o = 0; o < 4; ++o) {
            a0[o] = fmaf(rv[kx + o], w0, a0[o]);
            a1[o] = fmaf(rv[kx + o], w1v, a1[o]);
          }
        }
      }
#pragma unroll
      for (int ky = 0; ky < 5; ++ky) {
        float rv[8];
#pragma unroll
        for (int j = 0; j < 8; ++j) rv[j] = ts[u][(y + ky + 3) * 43 + x0 + 3 + j];
#pragma unroll
        for (int kx = 0; kx < 5; ++kx) {
          float w0 = w1c0[ky * 5 + kx], w1v = w1c1[ky * 5 + kx];
#pragma unroll
          for (int o = 0; o < 4; ++o) {
            a0[o] = fmaf(rv[kx + o], w0, a0[o]);
            a1[o] = fmaf(rv[kx + o], w1v, a1[o]);
          }
        }
      }
    }
  }
  float* pb = pbuf + ((size_t)(chunk * 32 + bg) * 2) * NPIX;
#pragma unroll
  for (int o = 0; o < 4; ++o) {
    int n = y * 32 + x0 + o;
    pb[n] = a0[o];
    pb[NPIX + n] = a1[o];
  }
}

__global__ __launch_bounds__(256) void conv_off_reduce(const float* __restrict__ pbuf,
                                                       float* __restrict__ offs) {
  int idx = blockIdx.x * 256 + threadIdx.x;
  float s = 0.f;
#pragma unroll
  for (int ch = 0; ch < 16; ++ch) s += pbuf[(size_t)ch * 65536 + idx];
  offs[idx] = tanhf(s) * 4.0f;
}

// ---------------- bilinear gather -> kvf bf16 [m=8192][c=384] ----------------
__global__ __launch_bounds__(256) void bilinear_kernel(const float* __restrict__ x,
    const float* __restrict__ offs, bf16s* __restrict__ kvf) {
  int chunk = blockIdx.x & 7, ntile = (blockIdx.x >> 3) & 3, bg = blockIdx.x >> 5;
  int n = ntile * 256 + threadIdx.x;
  int b = bg >> 2, g = bg & 3;
  int iy = n >> 5, ix = n & 31;
  float ys = (float)iy + offs[(size_t)bg * 2 * NPIX + n];
  float xs = (float)ix + offs[(size_t)bg * 2 * NPIX + NPIX + n];
  ys = fminf(fmaxf(ys, 0.f), 31.f);
  xs = fminf(fmaxf(xs, 0.f), 31.f);
  float y0f = floorf(ys), x0f = floorf(xs);
  int y0 = (int)y0f, x0 = (int)x0f;
  int y1 = min(y0 + 1, 31), x1 = min(x0 + 1, 31);
  float wy = ys - y0f, wx = xs - x0f;
  float w00 = (1.f - wy) * (1.f - wx), w01 = (1.f - wy) * wx;
  float w10 = wy * (1.f - wx), w11 = wy * wx;
  const float* xp = x + ((size_t)b * DIMC + g * OFFD + chunk * 12) * NPIX;
  bf16s* out = kvf + (size_t)(b * 1024 + n) * DIMC + g * OFFD + chunk * 12;
  int i00 = y0 * 32 + x0, i01 = y0 * 32 + x1, i10 = y1 * 32 + x0, i11 = y1 * 32 + x1;
#pragma unroll
  for (int cc = 0; cc < 12; ++cc) {
    const float* pl = xp + (size_t)cc * NPIX;
    out[cc] = f2b(w00 * pl[i00] + w01 * pl[i01] + w10 * pl[i10] + w11 * pl[i11]);
  }
}

// ---------------- MFMA flash attention v7: R7 structure + deferred l + V prefetch ----------------
// 1024 blocks; wave = 16 q-rows x 1024 keys (register-limited occupancy ~16 waves/CU:
// key-splitting the grid does NOT add residency — R8/R9 evidence).
// Padded-64 Q/K -> branchless b128 loads; l-reduction deferred to epilogue (pure sum);
// V rows prefetched one ks-step ahead to hide L2 latency.
__global__ __launch_bounds__(256) void flash_attn_kernel(
    const bf16s* __restrict__ qb, const bf16s* __restrict__ kb,
    const bf16s* __restrict__ vt, const float* __restrict__ scale,
    bf16s* __restrict__ out) {
  __shared__ short Ps[4][2][16 * 140];  // dbuf P, 35840 B
  int tid = threadIdx.x;
  int w = tid >> 6, lane = tid & 63;
  int quad = lane >> 4, l16 = lane & 15;
  int qt = blockIdx.x >> 6, bh = blockIdx.x & 63;  // XCD-local bh
  int b = bh >> 3, h = bh & 7;
  int q0 = qt * 64 + w * 16;
  float sc = scale[h] * 1.44269504f;

  const bf16s* qbase = qb + (size_t)bh * NPIX * 64;
  const bf16s* kbase = kb + (size_t)bh * NPIX * 64;
  const bf16s* vbase = vt + (size_t)bh * HDIM * NPIX;

  short8 bq0, bq1;
  {
    const bf16s* qrow = qbase + (size_t)(q0 + l16) * 64;
    short8 r0 = *(const short8*)(qrow + quad * 8);
    short8 r1 = *(const short8*)(qrow + 32 + quad * 8);
#pragma unroll
    for (int j = 0; j < 8; ++j) {
      bq0[j] = f2b(b2f(r0[j]) * sc);
      bq1[j] = f2b(b2f(r1[j]) * sc);
    }
  }
  float l_run = 0.f;  // per-lane partial; cross-lane reduce deferred to epilogue
  f32x4 O[3];
#pragma unroll
  for (int nt = 0; nt < 3; ++nt) O[nt] = (f32x4){0.f, 0.f, 0.f, 0.f};

#pragma unroll 2
  for (int kt = 0; kt < 8; ++kt) {
    int key0 = kt * 128;
    short* ps = &Ps[w][kt & 1][0];
    f32x4 Sv[8];
#pragma unroll
    for (int s = 0; s < 2; ++s)
#pragma unroll
      for (int nt = 0; nt < 4; ++nt) {
        const bf16s* krow = kbase + (size_t)(key0 + s * 64 + nt * 16 + l16) * 64;
        short8 ak0 = *(const short8*)(krow + quad * 8);
        short8 ak1 = *(const short8*)(krow + 32 + quad * 8);
        f32x4 acc = (f32x4){0.f, 0.f, 0.f, 0.f};
        acc = __builtin_amdgcn_mfma_f32_16x16x32_bf16(ak0, bq0, acc, 0, 0, 0);
        acc = __builtin_amdgcn_mfma_f32_16x16x32_bf16(ak1, bq1, acc, 0, 0, 0);
        Sv[s * 4 + nt] = acc;
      }
    float ls0 = 0.f, ls1 = 0.f, ls2 = 0.f, ls3 = 0.f;
#pragma unroll
    for (int i = 0; i < 8; i += 4) {
#pragma unroll
      for (int r = 0; r < 4; ++r) {
        float p0 = __builtin_amdgcn_exp2f(Sv[i][r]);
        float p1 = __builtin_amdgcn_exp2f(Sv[i + 1][r]);
        float p2 = __builtin_amdgcn_exp2f(Sv[i + 2][r]);
        float p3 = __builtin_amdgcn_exp2f(Sv[i + 3][r]);
        Sv[i][r] = p0; Sv[i + 1][r] = p1; Sv[i + 2][r] = p2; Sv[i + 3][r] = p3;
        ls0 += p0; ls1 += p1; ls2 += p2; ls3 += p3;
      }
    }
    l_run += (ls0 + ls1) + (ls2 + ls3);  // no shuffles here
#pragma unroll
    for (int s = 0; s < 2; ++s)
#pragma unroll
      for (int nt = 0; nt < 4; ++nt) {
        uint2 pk;
        pk.x = pk2(Sv[s * 4 + nt][0], Sv[s * 4 + nt][1]);
        pk.y = pk2(Sv[s * 4 + nt][2], Sv[s * 4 + nt][3]);
        *(uint2*)(ps + l16 * 140 + s * 64 + nt * 16 + quad * 4) = pk;
      }
    // PV with one-step V prefetch
    short8 bv[3];
#pragma unroll
    for (int nt = 0; nt < 3; ++nt)
      bv[nt] = *(const short8*)(vbase + (size_t)(nt * 16 + l16) * NPIX + key0 + quad * 8);
#pragma unroll
    for (int ks = 0; ks < 4; ++ks) {
      short8 ap = *(short8*)(ps + l16 * 140 + ks * 32 + quad * 8);
      short8 bvn[3];
      if (ks < 3) {
#pragma unroll
        for (int nt = 0; nt < 3; ++nt)
          bvn[nt] = *(const short8*)(vbase + (size_t)(nt * 16 + l16) * NPIX + key0 + (ks + 1) * 32 + quad * 8);
      }
#pragma unroll
      for (int nt = 0; nt < 3; ++nt)
        O[nt] = __builtin_amdgcn_mfma_f32_16x16x32_bf16(ap, bv[nt], O[nt], 0, 0, 0);
      if (ks < 3) {
#pragma unroll
        for (int nt = 0; nt < 3; ++nt) bv[nt] = bvn[nt];
      }
    }
  }
  // deferred cross-lane l reduction (once)
  l_run += __shfl_xor(l_run, 16, 64);
  l_run += __shfl_xor(l_run, 32, 64);
#pragma unroll
  for (int r = 0; r < 4; ++r) {
    float lr = __shfl(l_run, quad * 4 + r, 64);
    float inv = 1.0f / lr;
    int qrow = q0 + quad * 4 + r;
    bf16s* orow = out + ((size_t)(b * 1024 + qrow)) * DIMC + h * HDIM;
#pragma unroll
    for (int nt = 0; nt < 3; ++nt) orow[nt * 16 + l16] = f2b(O[nt][r] * inv);
  }
}

extern "C" void kernel_launch(void* const* d_in, const int* in_sizes, int n_in,
                              void* d_out, int out_size, void* d_ws, size_t ws_size,
                              hipStream_t stream) {
  const float* x  = (const float*)d_in[0];
  const float* Wq = (const float*)d_in[1];
  const float* Wk = (const float*)d_in[2];
  const float* Wv = (const float*)d_in[3];
  const float* Wp = (const float*)d_in[4];
  const float* bp = (const float*)d_in[5];
  const float* sc = (const float*)d_in[6];
  const float* W1 = (const float*)d_in[7];
  const float* W2 = (const float*)d_in[8];
  float* ws = (float*)d_ws;
  const size_t S = (size_t)BB * NPIX * DIMC;   // 3,145,728
  const size_t SP = (size_t)64 * NPIX * 64;    // 4,194,304 (padded Q/K)
  float* qg   = ws;
  float* offs = ws + S;
  float* pbuf = ws + S + 65536;
  bf16s* sb   = (bf16s*)(ws + S + 65536 + 1048576);
  bf16s* xh   = sb;                      // S; kbuf aliases xh+xl after Q GEMM
  bf16s* xl   = sb + S;                  // S
  bf16s* qbuf = sb + 2 * S;              // SP (padded)
  bf16s* kvfb = qbuf + SP;               // S
  bf16s* vbuf = kvfb + S;                // S
  bf16s* wqh  = vbuf + S;
  bf16s* wql  = wqh + 147456;
  bf16s* wkb  = wql + 147456;
  bf16s* wvb  = wkb + 147456;
  bf16s* wpb  = wvb + 147456;
  bf16s* attnout = (bf16s*)qg;
  bf16s* kbuf = xh;                      // SP fits in xh+xl (2S)

  hipMemsetAsync(qbuf, 0, SP * sizeof(bf16s), stream);
  prep_weights<<<2304, 256, 0, stream>>>(Wq, Wk, Wv, Wp, wqh, wql, wkb, wvb, wpb);
  transpose_split<<<dim3(16, 6, BB), 256, 0, stream>>>(x, xh, xl);
  gemm_lds<0><<<dim3(6, 128), 256, 0, stream>>>(xh, xl, wqh, wql, qg, qbuf, nullptr, nullptr);
  hipMemsetAsync(kbuf, 0, SP * sizeof(bf16s), stream);
  conv_off_part<<<512, 256, 0, stream>>>(qg, W1, W2, pbuf);
  conv_off_reduce<<<256, 256, 0, stream>>>(pbuf, offs);
  bilinear_kernel<<<1024, 256, 0, stream>>>(x, offs, kvfb);
  gemm_lds<1><<<dim3(6, 128), 256, 0, stream>>>(kvfb, nullptr, wkb, wvb, nullptr, kbuf, vbuf, nullptr);
  flash_attn_kernel<<<1024, 256, 0, stream>>>(qbuf, kbuf, vbuf, sc, attnout);
  gemm_lds<2><<<dim3(6, 128), 256, 0, stream>>>(attnout, nullptr, wpb, nullptr, (float*)d_out, nullptr, nullptr, bp);
}

// Round 12
// 255.267 us; speedup vs baseline: 1.1749x; 1.1749x over previous
//
#include <hip/hip_runtime.h>
#include <hip/hip_bf16.h>

#define DIMC 384
#define NHEADS 8
#define HDIM 48
#define OFFD 96
#define NPIX 1024
#define BB 8

typedef short bf16s;  // bf16 bits in short
typedef __attribute__((ext_vector_type(8))) short short8;
typedef __attribute__((ext_vector_type(4))) float f32x4;

__device__ __forceinline__ short f2b(float f) {
  union { float f; unsigned u; } v; v.f = f;
  unsigned r = (v.u + 0x7fffu + ((v.u >> 16) & 1u)) >> 16;
  return (short)r;
}
__device__ __forceinline__ float b2f(short s) {
  union { unsigned u; float f; } v; v.u = ((unsigned)(unsigned short)s) << 16; return v.f;
}
__device__ __forceinline__ unsigned pk2(float a, float b) {
  union { __hip_bfloat162 h; unsigned u; } v;
  v.h = __float22bfloat162_rn(float2{a, b});
  return v.u;
}

// ---------------- weight prep: Wq -> hi/lo bf16x2 ; Wk/Wv/Wp -> bf16 ----------------
__global__ __launch_bounds__(256) void prep_weights(
    const float* __restrict__ Wq, const float* __restrict__ Wk,
    const float* __restrict__ Wv, const float* __restrict__ Wp,
    bf16s* __restrict__ wqh, bf16s* __restrict__ wql,
    bf16s* __restrict__ wkb, bf16s* __restrict__ wvb, bf16s* __restrict__ wpb) {
  int idx = blockIdx.x * 256 + threadIdx.x;
  if (idx >= 4 * 147456) return;
  int which = idx / 147456, e = idx % 147456;
  if (which == 0) {
    float v = Wq[e]; short h = f2b(v);
    wqh[e] = h; wql[e] = f2b(v - b2f(h));
  } else if (which == 1) wkb[e] = f2b(Wk[e]);
  else if (which == 2) wvb[e] = f2b(Wv[e]);
  else wpb[e] = f2b(Wp[e]);
}

// ---------------- x (B,C,NPIX) fp32 -> x_hi/x_lo bf16 [m=8192][k=384] ----------------
__global__ __launch_bounds__(256) void transpose_split(const float* __restrict__ x,
    bf16s* __restrict__ xh, bf16s* __restrict__ xl) {
  __shared__ float ts[64][65];
  int np0 = blockIdx.x * 64, c0 = blockIdx.y * 64, b = blockIdx.z;
  int t = threadIdx.x;
  int a = t & 63, bq = t >> 6;
#pragma unroll
  for (int i = 0; i < 16; ++i) {
    int cl = bq + i * 4;
    ts[cl][a] = x[((size_t)(b * DIMC + c0 + cl)) * NPIX + np0 + a];
  }
  __syncthreads();
#pragma unroll
  for (int i = 0; i < 16; ++i) {
    int npl = bq + i * 4;
    float v = ts[a][npl];
    short h = f2b(v);
    size_t o = ((size_t)(b * NPIX + np0 + npl)) * DIMC + c0 + a;
    xh[o] = h; xl[o] = f2b(v - b2f(h));
  }
}

// ---------------- LDS-staged MFMA GEMM (R7-exact) ----------------
// MODE 0: Q bf16x3 (A=xh/xl, W=wqh/wql)  -> qg fp32 planar + qbuf bf16 [bh][n][48]
// MODE 1: KV fused (A=kvf, W=wk/wv)      -> K [bh][n][48], V [bh][d][n]
// MODE 2: proj     (A=attnout, W=wp)     -> fp32 NCHW + bias
template<int MODE>
__global__ __launch_bounds__(256) void gemm_lds(
    const bf16s* __restrict__ Ah, const bf16s* __restrict__ Al,
    const bf16s* __restrict__ Wa, const bf16s* __restrict__ Wb,
    float* __restrict__ outF, bf16s* __restrict__ outB, bf16s* __restrict__ outB2,
    const float* __restrict__ bias) {
  __shared__ __align__(16) short wlds[25600];  // 50 KB -> 3 blocks/CU
  const int NS  = (MODE == 2) ? 1 : 2;
  const int KCN = (MODE == 2) ? 48 : 24;
  const int STR = (MODE == 2) ? 392 : 200;
  int t = threadIdx.x;
  int w = t >> 6, lane = t & 63, quad = lane >> 4, l16 = lane & 15;
  int n0 = blockIdx.x * 64;
  int m0 = blockIdx.y * 64 + w * 16;
  f32x4 acc[4], acc2[4];
#pragma unroll
  for (int nt = 0; nt < 4; ++nt) {
    acc[nt] = (f32x4){0.f, 0.f, 0.f, 0.f};
    if (MODE != 2) acc2[nt] = (f32x4){0.f, 0.f, 0.f, 0.f};
  }
  const bf16s* arow_a = Ah + (size_t)(m0 + l16) * DIMC;
  const bf16s* arow_l = (MODE == 0) ? (Al + (size_t)(m0 + l16) * DIMC) : nullptr;

  for (int s = 0; s < NS; ++s) {
    if (s) __syncthreads();
    int kcb = s * 24;
#pragma unroll
    for (int ii = 0; ii < (KCN * 64) / 256; ++ii) {
      int i = ii * 256 + t;
      int n = i / KCN, kcl = i % KCN;
      *(short8*)(&wlds[n * STR + kcl * 8]) =
          *(const short8*)(Wa + (size_t)(n0 + n) * DIMC + (kcb + kcl) * 8);
      if (MODE != 2)
        *(short8*)(&wlds[12800 + n * STR + kcl * 8]) =
            *(const short8*)(Wb + (size_t)(n0 + n) * DIMC + (kcb + kcl) * 8);
    }
    __syncthreads();
    int k0beg = s * 6, k0cnt = (MODE == 2) ? 12 : 6;
#pragma unroll
    for (int kk = 0; kk < k0cnt; ++kk) {
      int k0 = k0beg + kk;
      short8 a0 = *(const short8*)(arow_a + k0 * 32 + quad * 8);
      short8 a1;
      if (MODE == 0) a1 = *(const short8*)(arow_l + k0 * 32 + quad * 8);
      int kcl = kk * 4 + quad;
#pragma unroll
      for (int nt = 0; nt < 4; ++nt) {
        int n = nt * 16 + l16;
        short8 b0 = *(const short8*)(&wlds[n * STR + kcl * 8]);
        acc[nt] = __builtin_amdgcn_mfma_f32_16x16x32_bf16(a0, b0, acc[nt], 0, 0, 0);
        if (MODE == 0) {
          short8 b1 = *(const short8*)(&wlds[12800 + n * STR + kcl * 8]);
          acc[nt] = __builtin_amdgcn_mfma_f32_16x16x32_bf16(a1, b0, acc[nt], 0, 0, 0);
          acc[nt] = __builtin_amdgcn_mfma_f32_16x16x32_bf16(a0, b1, acc[nt], 0, 0, 0);
        } else if (MODE == 1) {
          short8 b1 = *(const short8*)(&wlds[12800 + n * STR + kcl * 8]);
          acc2[nt] = __builtin_amdgcn_mfma_f32_16x16x32_bf16(a0, b1, acc2[nt], 0, 0, 0);
        }
      }
    }
  }
#pragma unroll
  for (int nt = 0; nt < 4; ++nt) {
    int c = n0 + nt * 16 + l16;
#pragma unroll
    for (int r = 0; r < 4; ++r) {
      int m = m0 + quad * 4 + r;
      int b = m >> 10, np = m & 1023;
      float v = acc[nt][r];
      if (MODE == 0) {
        int g = c / OFFD, cc = c % OFFD;
        outF[((size_t)((b * 4 + g) * OFFD + cc)) * NPIX + np] = v;
        int h = c / HDIM, d = c % HDIM;
        outB[((size_t)((b * 8 + h) * NPIX + np)) * HDIM + d] = f2b(v);
      } else if (MODE == 1) {
        int h = c / HDIM, d = c % HDIM;
        outB[((size_t)((b * 8 + h) * NPIX + np)) * HDIM + d] = f2b(v);
        outB2[((size_t)((b * 8 + h) * HDIM + d)) * NPIX + np] = f2b(acc2[nt][r]);
      } else {
        outF[((size_t)(b * DIMC + c)) * NPIX + np] = v + bias[c];
      }
    }
  }
}

// ---------------- offset convs: register-tiled, 2 channels per barrier ----------------
__global__ __launch_bounds__(256) void conv_off_part(const float* __restrict__ qg,
    const float* __restrict__ W1, const float* __restrict__ W2, float* __restrict__ pbuf) {
  __shared__ float ts[2][42 * 43];
  int chunk = blockIdx.x & 15, bg = blockIdx.x >> 4;
  int t = threadIdx.x;
  int y = t >> 3, x0 = (t & 7) * 4;
  float a0[4] = {0.f, 0.f, 0.f, 0.f}, a1[4] = {0.f, 0.f, 0.f, 0.f};
  const float* plane0 = qg + (size_t)bg * OFFD * NPIX;
  for (int ci2 = 0; ci2 < 3; ++ci2) {
    int ccb = chunk * 6 + ci2 * 2;
    __syncthreads();
    for (int e = t; e < 2 * 42 * 42; e += 256) {
      int u = e >= 42 * 42;
      int e2 = e - u * 42 * 42;
      int r = e2 / 42, c = e2 - r * 42;
      int gy = r - 5, gx = c - 5;
      const float* plane = plane0 + (size_t)(ccb + u) * NPIX;
      ts[u][r * 43 + c] = (gy >= 0 && gy < 32 && gx >= 0 && gx < 32) ? plane[gy * 32 + gx] : 0.f;
    }
    __syncthreads();
#pragma unroll
    for (int u = 0; u < 2; ++u) {
      int cc = ccb + u;
      const float* w1c0 = W1 + (size_t)cc * 25;
      const float* w1c1 = W1 + (size_t)(OFFD + cc) * 25;
      const float* w2c0 = W2 + (size_t)cc * 121;
      const float* w2c1 = W2 + (size_t)(OFFD + cc) * 121;
#pragma unroll
      for (int ky = 0; ky < 11; ++ky) {
        float rv[14];
#pragma unroll
        for (int j = 0; j < 14; ++j) rv[j] = ts[u][(y + ky) * 43 + x0 + j];
#pragma unroll
        for (int kx = 0; kx < 11; ++kx) {
          float w0 = w2c0[ky * 11 + kx], w1v = w2c1[ky * 11 + kx];
#pragma unroll
          for (int o = 0; o < 4; ++o) {
            a0[o] = fmaf(rv[kx + o], w0, a0[o]);
            a1[o] = fmaf(rv[kx + o], w1v, a1[o]);
          }
        }
      }
#pragma unroll
      for (int ky = 0; ky < 5; ++ky) {
        float rv[8];
#pragma unroll
        for (int j = 0; j < 8; ++j) rv[j] = ts[u][(y + ky + 3) * 43 + x0 + 3 + j];
#pragma unroll
        for (int kx = 0; kx < 5; ++kx) {
          float w0 = w1c0[ky * 5 + kx], w1v = w1c1[ky * 5 + kx];
#pragma unroll
          for (int o = 0; o < 4; ++o) {
            a0[o] = fmaf(rv[kx + o], w0, a0[o]);
            a1[o] = fmaf(rv[kx + o], w1v, a1[o]);
          }
        }
      }
    }
  }
  float* pb = pbuf + ((size_t)(chunk * 32 + bg) * 2) * NPIX;
#pragma unroll
  for (int o = 0; o < 4; ++o) {
    int n = y * 32 + x0 + o;
    pb[n] = a0[o];
    pb[NPIX + n] = a1[o];
  }
}

// ---------------- bilinear gather (fused 16-chunk conv reduce + tanh) ----------------
// offs_y/x computed in-kernel from pbuf partials: Σ over 16 channel chunks, tanh, ×4.
__global__ __launch_bounds__(256) void bilinear_kernel(const float* __restrict__ x,
    const float* __restrict__ pbuf, bf16s* __restrict__ kvf) {
  int chunk = blockIdx.x & 7, ntile = (blockIdx.x >> 3) & 3, bg = blockIdx.x >> 5;
  int n = ntile * 256 + threadIdx.x;
  int b = bg >> 2, g = bg & 3;
  int iy = n >> 5, ix = n & 31;
  float s0 = 0.f, s1 = 0.f;
#pragma unroll
  for (int ch = 0; ch < 16; ++ch) {
    const float* pb = pbuf + ((size_t)(ch * 32 + bg) * 2) * NPIX;
    s0 += pb[n];
    s1 += pb[NPIX + n];
  }
  float ys = (float)iy + tanhf(s0) * 4.0f;
  float xs = (float)ix + tanhf(s1) * 4.0f;
  ys = fminf(fmaxf(ys, 0.f), 31.f);
  xs = fminf(fmaxf(xs, 0.f), 31.f);
  float y0f = floorf(ys), x0f = floorf(xs);
  int y0 = (int)y0f, x0 = (int)x0f;
  int y1 = min(y0 + 1, 31), x1 = min(x0 + 1, 31);
  float wy = ys - y0f, wx = xs - x0f;
  float w00 = (1.f - wy) * (1.f - wx), w01 = (1.f - wy) * wx;
  float w10 = wy * (1.f - wx), w11 = wy * wx;
  const float* xp = x + ((size_t)b * DIMC + g * OFFD + chunk * 12) * NPIX;
  bf16s* out = kvf + (size_t)(b * 1024 + n) * DIMC + g * OFFD + chunk * 12;
  int i00 = y0 * 32 + x0, i01 = y0 * 32 + x1, i10 = y1 * 32 + x0, i11 = y1 * 32 + x1;
#pragma unroll
  for (int cc = 0; cc < 12; ++cc) {
    const float* pl = xp + (size_t)cc * NPIX;
    out[cc] = f2b(w00 * pl[i00] + w01 * pl[i01] + w10 * pl[i10] + w11 * pl[i11]);
  }
}

// ---------------- MFMA flash attention (R7-exact: measured 68.3 us) ----------------
__global__ __launch_bounds__(256) void flash_attn_kernel(
    const bf16s* __restrict__ qb, const bf16s* __restrict__ kb,
    const bf16s* __restrict__ vt, const float* __restrict__ scale,
    bf16s* __restrict__ out) {
  __shared__ short Ps[4][2][16 * 140];
  int tid = threadIdx.x;
  int w = tid >> 6, lane = tid & 63;
  int quad = lane >> 4, l16 = lane & 15;
  int qt = blockIdx.x >> 6, bh = blockIdx.x & 63;  // XCD-aware decode
  int b = bh >> 3, h = bh & 7;
  int q0 = qt * 64 + w * 16;
  float sc = scale[h] * 1.44269504f;

  const bf16s* qbase = qb + (size_t)bh * NPIX * HDIM;
  const bf16s* kbase = kb + (size_t)bh * NPIX * HDIM;
  const bf16s* vbase = vt + (size_t)bh * HDIM * NPIX;

  short8 bq0, bq1;
  {
    const bf16s* qrow = qbase + (size_t)(q0 + l16) * HDIM;
    short8 r0 = *(const short8*)(qrow + quad * 8);
    short8 r1;
    if (quad < 2) r1 = *(const short8*)(qrow + 32 + quad * 8);
    else { short8 z = {0,0,0,0,0,0,0,0}; r1 = z; }
#pragma unroll
    for (int j = 0; j < 8; ++j) {
      bq0[j] = f2b(b2f(r0[j]) * sc);
      bq1[j] = f2b(b2f(r1[j]) * sc);
    }
  }
  float l_run = 0.f;
  f32x4 O[3];
#pragma unroll
  for (int nt = 0; nt < 3; ++nt) O[nt] = (f32x4){0.f, 0.f, 0.f, 0.f};

#pragma unroll 2
  for (int kt = 0; kt < 8; ++kt) {
    int key0 = kt * 128;
    short* ps = &Ps[w][kt & 1][0];
    f32x4 Sv[8];
#pragma unroll
    for (int s = 0; s < 2; ++s)
#pragma unroll
      for (int nt = 0; nt < 4; ++nt) {
        const bf16s* krow = kbase + (size_t)(key0 + s * 64 + nt * 16 + l16) * HDIM;
        short8 ak0 = *(const short8*)(krow + quad * 8);
        short8 ak1;
        if (quad < 2) ak1 = *(const short8*)(krow + 32 + quad * 8);
        else { short8 z = {0,0,0,0,0,0,0,0}; ak1 = z; }
        f32x4 acc = (f32x4){0.f, 0.f, 0.f, 0.f};
        acc = __builtin_amdgcn_mfma_f32_16x16x32_bf16(ak0, bq0, acc, 0, 0, 0);
        acc = __builtin_amdgcn_mfma_f32_16x16x32_bf16(ak1, bq1, acc, 0, 0, 0);
        Sv[s * 4 + nt] = acc;
      }
    float ls0 = 0.f, ls1 = 0.f, ls2 = 0.f, ls3 = 0.f;
#pragma unroll
    for (int i = 0; i < 8; i += 4) {
#pragma unroll
      for (int r = 0; r < 4; ++r) {
        float p0 = __builtin_amdgcn_exp2f(Sv[i][r]);
        float p1 = __builtin_amdgcn_exp2f(Sv[i + 1][r]);
        float p2 = __builtin_amdgcn_exp2f(Sv[i + 2][r]);
        float p3 = __builtin_amdgcn_exp2f(Sv[i + 3][r]);
        Sv[i][r] = p0; Sv[i + 1][r] = p1; Sv[i + 2][r] = p2; Sv[i + 3][r] = p3;
        ls0 += p0; ls1 += p1; ls2 += p2; ls3 += p3;
      }
    }
    float ls = (ls0 + ls1) + (ls2 + ls3);
    ls += __shfl_xor(ls, 16, 64);
    ls += __shfl_xor(ls, 32, 64);
    l_run += ls;
#pragma unroll
    for (int s = 0; s < 2; ++s)
#pragma unroll
      for (int nt = 0; nt < 4; ++nt) {
        uint2 pk;
        pk.x = pk2(Sv[s * 4 + nt][0], Sv[s * 4 + nt][1]);
        pk.y = pk2(Sv[s * 4 + nt][2], Sv[s * 4 + nt][3]);
        *(uint2*)(ps + l16 * 140 + s * 64 + nt * 16 + quad * 4) = pk;
      }
#pragma unroll
    for (int ks = 0; ks < 4; ++ks) {
      short8 ap = *(short8*)(ps + l16 * 140 + ks * 32 + quad * 8);
#pragma unroll
      for (int nt = 0; nt < 3; ++nt) {
        const bf16s* vrow = vbase + (size_t)(nt * 16 + l16) * NPIX + key0 + ks * 32;
        short8 bv = *(const short8*)(vrow + quad * 8);
        O[nt] = __builtin_amdgcn_mfma_f32_16x16x32_bf16(ap, bv, O[nt], 0, 0, 0);
      }
    }
  }
#pragma unroll
  for (int r = 0; r < 4; ++r) {
    float lr = __shfl(l_run, quad * 4 + r, 64);
    float inv = 1.0f / lr;
    int qrow = q0 + quad * 4 + r;
    bf16s* orow = out + ((size_t)(b * 1024 + qrow)) * DIMC + h * HDIM;
#pragma unroll
    for (int nt = 0; nt < 3; ++nt) orow[nt * 16 + l16] = f2b(O[nt][r] * inv);
  }
}

extern "C" void kernel_launch(void* const* d_in, const int* in_sizes, int n_in,
                              void* d_out, int out_size, void* d_ws, size_t ws_size,
                              hipStream_t stream) {
  const float* x  = (const float*)d_in[0];
  const float* Wq = (const float*)d_in[1];
  const float* Wk = (const float*)d_in[2];
  const float* Wv = (const float*)d_in[3];
  const float* Wp = (const float*)d_in[4];
  const float* bp = (const float*)d_in[5];
  const float* sc = (const float*)d_in[6];
  const float* W1 = (const float*)d_in[7];
  const float* W2 = (const float*)d_in[8];
  float* ws = (float*)d_ws;
  const size_t S = (size_t)BB * NPIX * DIMC;  // 3,145,728
  float* qg   = ws;
  float* pbuf = ws + S;                  // 1,048,576
  bf16s* sb   = (bf16s*)(ws + S + 1048576);
  bf16s* xh   = sb;                      // aliased as kbuf after Q GEMM
  bf16s* xl   = sb + S;                  // aliased as vbuf
  bf16s* qbuf = sb + 2 * S;
  bf16s* kvfb = sb + 3 * S;
  bf16s* wqh  = sb + 4 * S;
  bf16s* wql  = wqh + 147456;
  bf16s* wkb  = wql + 147456;
  bf16s* wvb  = wkb + 147456;
  bf16s* wpb  = wvb + 147456;
  bf16s* attnout = (bf16s*)qg;
  bf16s* kbuf = xh;
  bf16s* vbuf = xl;

  prep_weights<<<2304, 256, 0, stream>>>(Wq, Wk, Wv, Wp, wqh, wql, wkb, wvb, wpb);
  transpose_split<<<dim3(16, 6, BB), 256, 0, stream>>>(x, xh, xl);
  gemm_lds<0><<<dim3(6, 128), 256, 0, stream>>>(xh, xl, wqh, wql, qg, qbuf, nullptr, nullptr);
  conv_off_part<<<512, 256, 0, stream>>>(qg, W1, W2, pbuf);
  bilinear_kernel<<<1024, 256, 0, stream>>>(x, pbuf, kvfb);
  gemm_lds<1><<<dim3(6, 128), 256, 0, stream>>>(kvfb, nullptr, wkb, wvb, nullptr, kbuf, vbuf, nullptr);
  flash_attn_kernel<<<1024, 256, 0, stream>>>(qbuf, kbuf, vbuf, sc, attnout);
  gemm_lds<2><<<dim3(6, 128), 256, 0, stream>>>(attnout, nullptr, wpb, nullptr, (float*)d_out, nullptr, nullptr, bp);
}

// Round 13
// 254.715 us; speedup vs baseline: 1.1774x; 1.0022x over previous
//
#include <hip/hip_runtime.h>
#include <hip/hip_bf16.h>

#define DIMC 384
#define NHEADS 8
#define HDIM 48
#define OFFD 96
#define NPIX 1024
#define BB 8

typedef short bf16s;  // bf16 bits in short
typedef __attribute__((ext_vector_type(8))) short short8;
typedef __attribute__((ext_vector_type(4))) float f32x4;

__device__ __forceinline__ short f2b(float f) {
  union { float f; unsigned u; } v; v.f = f;
  unsigned r = (v.u + 0x7fffu + ((v.u >> 16) & 1u)) >> 16;
  return (short)r;
}
__device__ __forceinline__ float b2f(short s) {
  union { unsigned u; float f; } v; v.u = ((unsigned)(unsigned short)s) << 16; return v.f;
}
__device__ __forceinline__ unsigned pk2(float a, float b) {
  union { __hip_bfloat162 h; unsigned u; } v;
  v.h = __float22bfloat162_rn(float2{a, b});
  return v.u;
}

// ---------------- weight prep: Wq -> hi/lo bf16x2 ; Wk/Wv/Wp -> bf16 ----------------
__global__ __launch_bounds__(256) void prep_weights(
    const float* __restrict__ Wq, const float* __restrict__ Wk,
    const float* __restrict__ Wv, const float* __restrict__ Wp,
    bf16s* __restrict__ wqh, bf16s* __restrict__ wql,
    bf16s* __restrict__ wkb, bf16s* __restrict__ wvb, bf16s* __restrict__ wpb) {
  int idx = blockIdx.x * 256 + threadIdx.x;
  if (idx >= 4 * 147456) return;
  int which = idx / 147456, e = idx % 147456;
  if (which == 0) {
    float v = Wq[e]; short h = f2b(v);
    wqh[e] = h; wql[e] = f2b(v - b2f(h));
  } else if (which == 1) wkb[e] = f2b(Wk[e]);
  else if (which == 2) wvb[e] = f2b(Wv[e]);
  else wpb[e] = f2b(Wp[e]);
}

// ---------------- x (B,C,NPIX) fp32 -> x_hi/x_lo bf16 [m=8192][k=384] ----------------
__global__ __launch_bounds__(256) void transpose_split(const float* __restrict__ x,
    bf16s* __restrict__ xh, bf16s* __restrict__ xl) {
  __shared__ float ts[64][65];
  int np0 = blockIdx.x * 64, c0 = blockIdx.y * 64, b = blockIdx.z;
  int t = threadIdx.x;
  int a = t & 63, bq = t >> 6;
#pragma unroll
  for (int i = 0; i < 16; ++i) {
    int cl = bq + i * 4;
    ts[cl][a] = x[((size_t)(b * DIMC + c0 + cl)) * NPIX + np0 + a];
  }
  __syncthreads();
#pragma unroll
  for (int i = 0; i < 16; ++i) {
    int npl = bq + i * 4;
    float v = ts[a][npl];
    short h = f2b(v);
    size_t o = ((size_t)(b * NPIX + np0 + npl)) * DIMC + c0 + a;
    xh[o] = h; xl[o] = f2b(v - b2f(h));
  }
}

// ---------------- LDS-staged MFMA GEMM (R7-exact) ----------------
// MODE 0: Q bf16x3 (A=xh/xl, W=wqh/wql)  -> qg fp32 planar + qbuf bf16 [bh][n][48]
// MODE 1: KV fused (A=kvf, W=wk/wv)      -> K [bh][n][48], V [bh][d][n]
// MODE 2: proj     (A=attnout, W=wp)     -> fp32 NCHW + bias
template<int MODE>
__global__ __launch_bounds__(256) void gemm_lds(
    const bf16s* __restrict__ Ah, const bf16s* __restrict__ Al,
    const bf16s* __restrict__ Wa, const bf16s* __restrict__ Wb,
    float* __restrict__ outF, bf16s* __restrict__ outB, bf16s* __restrict__ outB2,
    const float* __restrict__ bias) {
  __shared__ __align__(16) short wlds[25600];  // 50 KB -> 3 blocks/CU
  const int NS  = (MODE == 2) ? 1 : 2;
  const int KCN = (MODE == 2) ? 48 : 24;
  const int STR = (MODE == 2) ? 392 : 200;
  int t = threadIdx.x;
  int w = t >> 6, lane = t & 63, quad = lane >> 4, l16 = lane & 15;
  int n0 = blockIdx.x * 64;
  int m0 = blockIdx.y * 64 + w * 16;
  f32x4 acc[4], acc2[4];
#pragma unroll
  for (int nt = 0; nt < 4; ++nt) {
    acc[nt] = (f32x4){0.f, 0.f, 0.f, 0.f};
    if (MODE != 2) acc2[nt] = (f32x4){0.f, 0.f, 0.f, 0.f};
  }
  const bf16s* arow_a = Ah + (size_t)(m0 + l16) * DIMC;
  const bf16s* arow_l = (MODE == 0) ? (Al + (size_t)(m0 + l16) * DIMC) : nullptr;

  for (int s = 0; s < NS; ++s) {
    if (s) __syncthreads();
    int kcb = s * 24;
#pragma unroll
    for (int ii = 0; ii < (KCN * 64) / 256; ++ii) {
      int i = ii * 256 + t;
      int n = i / KCN, kcl = i % KCN;
      *(short8*)(&wlds[n * STR + kcl * 8]) =
          *(const short8*)(Wa + (size_t)(n0 + n) * DIMC + (kcb + kcl) * 8);
      if (MODE != 2)
        *(short8*)(&wlds[12800 + n * STR + kcl * 8]) =
            *(const short8*)(Wb + (size_t)(n0 + n) * DIMC + (kcb + kcl) * 8);
    }
    __syncthreads();
    int k0beg = s * 6, k0cnt = (MODE == 2) ? 12 : 6;
#pragma unroll
    for (int kk = 0; kk < k0cnt; ++kk) {
      int k0 = k0beg + kk;
      short8 a0 = *(const short8*)(arow_a + k0 * 32 + quad * 8);
      short8 a1;
      if (MODE == 0) a1 = *(const short8*)(arow_l + k0 * 32 + quad * 8);
      int kcl = kk * 4 + quad;
#pragma unroll
      for (int nt = 0; nt < 4; ++nt) {
        int n = nt * 16 + l16;
        short8 b0 = *(const short8*)(&wlds[n * STR + kcl * 8]);
        acc[nt] = __builtin_amdgcn_mfma_f32_16x16x32_bf16(a0, b0, acc[nt], 0, 0, 0);
        if (MODE == 0) {
          short8 b1 = *(const short8*)(&wlds[12800 + n * STR + kcl * 8]);
          acc[nt] = __builtin_amdgcn_mfma_f32_16x16x32_bf16(a1, b0, acc[nt], 0, 0, 0);
          acc[nt] = __builtin_amdgcn_mfma_f32_16x16x32_bf16(a0, b1, acc[nt], 0, 0, 0);
        } else if (MODE == 1) {
          short8 b1 = *(const short8*)(&wlds[12800 + n * STR + kcl * 8]);
          acc2[nt] = __builtin_amdgcn_mfma_f32_16x16x32_bf16(a0, b1, acc2[nt], 0, 0, 0);
        }
      }
    }
  }
#pragma unroll
  for (int nt = 0; nt < 4; ++nt) {
    int c = n0 + nt * 16 + l16;
#pragma unroll
    for (int r = 0; r < 4; ++r) {
      int m = m0 + quad * 4 + r;
      int b = m >> 10, np = m & 1023;
      float v = acc[nt][r];
      if (MODE == 0) {
        int g = c / OFFD, cc = c % OFFD;
        outF[((size_t)((b * 4 + g) * OFFD + cc)) * NPIX + np] = v;
        int h = c / HDIM, d = c % HDIM;
        outB[((size_t)((b * 8 + h) * NPIX + np)) * HDIM + d] = f2b(v);
      } else if (MODE == 1) {
        int h = c / HDIM, d = c % HDIM;
        outB[((size_t)((b * 8 + h) * NPIX + np)) * HDIM + d] = f2b(v);
        outB2[((size_t)((b * 8 + h) * HDIM + d)) * NPIX + np] = f2b(acc2[nt][r]);
      } else {
        outF[((size_t)(b * DIMC + c)) * NPIX + np] = v + bias[c];
      }
    }
  }
}

// ---------------- offset convs: register-tiled, 2ch/barrier, fused 5x5 ----------------
// 5x5 tap window (rows y+3..y+7, cols x0+3..x0+10) is a subset of the 11x11 row
// registers rv[14] -> do its FMAs inside the ky sweep; second LDS read loop deleted.
__global__ __launch_bounds__(256) void conv_off_part(const float* __restrict__ qg,
    const float* __restrict__ W1, const float* __restrict__ W2, float* __restrict__ pbuf) {
  __shared__ float ts[2][42 * 43];
  int chunk = blockIdx.x & 15, bg = blockIdx.x >> 4;
  int t = threadIdx.x;
  int y = t >> 3, x0 = (t & 7) * 4;
  float a0[4] = {0.f, 0.f, 0.f, 0.f}, a1[4] = {0.f, 0.f, 0.f, 0.f};
  const float* plane0 = qg + (size_t)bg * OFFD * NPIX;
  for (int ci2 = 0; ci2 < 3; ++ci2) {
    int ccb = chunk * 6 + ci2 * 2;
    __syncthreads();
    for (int e = t; e < 2 * 42 * 42; e += 256) {
      int u = e >= 42 * 42;
      int e2 = e - u * 42 * 42;
      int r = e2 / 42, c = e2 - r * 42;
      int gy = r - 5, gx = c - 5;
      const float* plane = plane0 + (size_t)(ccb + u) * NPIX;
      ts[u][r * 43 + c] = (gy >= 0 && gy < 32 && gx >= 0 && gx < 32) ? plane[gy * 32 + gx] : 0.f;
    }
    __syncthreads();
#pragma unroll
    for (int u = 0; u < 2; ++u) {
      int cc = ccb + u;
      const float* w1c0 = W1 + (size_t)cc * 25;
      const float* w1c1 = W1 + (size_t)(OFFD + cc) * 25;
      const float* w2c0 = W2 + (size_t)cc * 121;
      const float* w2c1 = W2 + (size_t)(OFFD + cc) * 121;
#pragma unroll
      for (int ky = 0; ky < 11; ++ky) {
        float rv[14];
#pragma unroll
        for (int j = 0; j < 14; ++j) rv[j] = ts[u][(y + ky) * 43 + x0 + j];
#pragma unroll
        for (int kx = 0; kx < 11; ++kx) {
          float w0 = w2c0[ky * 11 + kx], w1v = w2c1[ky * 11 + kx];
#pragma unroll
          for (int o = 0; o < 4; ++o) {
            a0[o] = fmaf(rv[kx + o], w0, a0[o]);
            a1[o] = fmaf(rv[kx + o], w1v, a1[o]);
          }
        }
        if (ky >= 3 && ky <= 7) {  // 5x5 from the same row registers
          int ky5 = ky - 3;
#pragma unroll
          for (int kx = 0; kx < 5; ++kx) {
            float w0 = w1c0[ky5 * 5 + kx], w1v = w1c1[ky5 * 5 + kx];
#pragma unroll
            for (int o = 0; o < 4; ++o) {
              a0[o] = fmaf(rv[3 + kx + o], w0, a0[o]);
              a1[o] = fmaf(rv[3 + kx + o], w1v, a1[o]);
            }
          }
        }
      }
    }
  }
  float* pb = pbuf + ((size_t)(chunk * 32 + bg) * 2) * NPIX;
#pragma unroll
  for (int o = 0; o < 4; ++o) {
    int n = y * 32 + x0 + o;
    pb[n] = a0[o];
    pb[NPIX + n] = a1[o];
  }
}

__global__ __launch_bounds__(256) void conv_off_reduce(const float* __restrict__ pbuf,
                                                       float* __restrict__ offs) {
  int idx = blockIdx.x * 256 + threadIdx.x;  // 65536
  float s = 0.f;
#pragma unroll
  for (int ch = 0; ch < 16; ++ch) s += pbuf[(size_t)ch * 65536 + idx];
  offs[idx] = tanhf(s) * 4.0f;
}

// ---------------- bilinear gather -> kvf bf16 [m=8192][c=384] ----------------
__global__ __launch_bounds__(256) void bilinear_kernel(const float* __restrict__ x,
    const float* __restrict__ offs, bf16s* __restrict__ kvf) {
  int chunk = blockIdx.x & 7, ntile = (blockIdx.x >> 3) & 3, bg = blockIdx.x >> 5;
  int n = ntile * 256 + threadIdx.x;
  int b = bg >> 2, g = bg & 3;
  int iy = n >> 5, ix = n & 31;
  float ys = (float)iy + offs[(size_t)bg * 2 * NPIX + n];
  float xs = (float)ix + offs[(size_t)bg * 2 * NPIX + NPIX + n];
  ys = fminf(fmaxf(ys, 0.f), 31.f);
  xs = fminf(fmaxf(xs, 0.f), 31.f);
  float y0f = floorf(ys), x0f = floorf(xs);
  int y0 = (int)y0f, x0 = (int)x0f;
  int y1 = min(y0 + 1, 31), x1 = min(x0 + 1, 31);
  float wy = ys - y0f, wx = xs - x0f;
  float w00 = (1.f - wy) * (1.f - wx), w01 = (1.f - wy) * wx;
  float w10 = wy * (1.f - wx), w11 = wy * wx;
  const float* xp = x + ((size_t)b * DIMC + g * OFFD + chunk * 12) * NPIX;
  bf16s* out = kvf + (size_t)(b * 1024 + n) * DIMC + g * OFFD + chunk * 12;
  int i00 = y0 * 32 + x0, i01 = y0 * 32 + x1, i10 = y1 * 32 + x0, i11 = y1 * 32 + x1;
#pragma unroll
  for (int cc = 0; cc < 12; ++cc) {
    const float* pl = xp + (size_t)cc * NPIX;
    out[cc] = f2b(w00 * pl[i00] + w01 * pl[i01] + w10 * pl[i10] + w11 * pl[i11]);
  }
}

// ---------------- MFMA flash attention (R7-exact: measured ~69 us) ----------------
__global__ __launch_bounds__(256) void flash_attn_kernel(
    const bf16s* __restrict__ qb, const bf16s* __restrict__ kb,
    const bf16s* __restrict__ vt, const float* __restrict__ scale,
    bf16s* __restrict__ out) {
  __shared__ short Ps[4][2][16 * 140];
  int tid = threadIdx.x;
  int w = tid >> 6, lane = tid & 63;
  int quad = lane >> 4, l16 = lane & 15;
  int qt = blockIdx.x >> 6, bh = blockIdx.x & 63;  // XCD-aware decode
  int b = bh >> 3, h = bh & 7;
  int q0 = qt * 64 + w * 16;
  float sc = scale[h] * 1.44269504f;

  const bf16s* qbase = qb + (size_t)bh * NPIX * HDIM;
  const bf16s* kbase = kb + (size_t)bh * NPIX * HDIM;
  const bf16s* vbase = vt + (size_t)bh * HDIM * NPIX;

  short8 bq0, bq1;
  {
    const bf16s* qrow = qbase + (size_t)(q0 + l16) * HDIM;
    short8 r0 = *(const short8*)(qrow + quad * 8);
    short8 r1;
    if (quad < 2) r1 = *(const short8*)(qrow + 32 + quad * 8);
    else { short8 z = {0,0,0,0,0,0,0,0}; r1 = z; }
#pragma unroll
    for (int j = 0; j < 8; ++j) {
      bq0[j] = f2b(b2f(r0[j]) * sc);
      bq1[j] = f2b(b2f(r1[j]) * sc);
    }
  }
  float l_run = 0.f;
  f32x4 O[3];
#pragma unroll
  for (int nt = 0; nt < 3; ++nt) O[nt] = (f32x4){0.f, 0.f, 0.f, 0.f};

#pragma unroll 2
  for (int kt = 0; kt < 8; ++kt) {
    int key0 = kt * 128;
    short* ps = &Ps[w][kt & 1][0];
    f32x4 Sv[8];
#pragma unroll
    for (int s = 0; s < 2; ++s)
#pragma unroll
      for (int nt = 0; nt < 4; ++nt) {
        const bf16s* krow = kbase + (size_t)(key0 + s * 64 + nt * 16 + l16) * HDIM;
        short8 ak0 = *(const short8*)(krow + quad * 8);
        short8 ak1;
        if (quad < 2) ak1 = *(const short8*)(krow + 32 + quad * 8);
        else { short8 z = {0,0,0,0,0,0,0,0}; ak1 = z; }
        f32x4 acc = (f32x4){0.f, 0.f, 0.f, 0.f};
        acc = __builtin_amdgcn_mfma_f32_16x16x32_bf16(ak0, bq0, acc, 0, 0, 0);
        acc = __builtin_amdgcn_mfma_f32_16x16x32_bf16(ak1, bq1, acc, 0, 0, 0);
        Sv[s * 4 + nt] = acc;
      }
    float ls0 = 0.f, ls1 = 0.f, ls2 = 0.f, ls3 = 0.f;
#pragma unroll
    for (int i = 0; i < 8; i += 4) {
#pragma unroll
      for (int r = 0; r < 4; ++r) {
        float p0 = __builtin_amdgcn_exp2f(Sv[i][r]);
        float p1 = __builtin_amdgcn_exp2f(Sv[i + 1][r]);
        float p2 = __builtin_amdgcn_exp2f(Sv[i + 2][r]);
        float p3 = __builtin_amdgcn_exp2f(Sv[i + 3][r]);
        Sv[i][r] = p0; Sv[i + 1][r] = p1; Sv[i + 2][r] = p2; Sv[i + 3][r] = p3;
        ls0 += p0; ls1 += p1; ls2 += p2; ls3 += p3;
      }
    }
    float ls = (ls0 + ls1) + (ls2 + ls3);
    ls += __shfl_xor(ls, 16, 64);
    ls += __shfl_xor(ls, 32, 64);
    l_run += ls;
#pragma unroll
    for (int s = 0; s < 2; ++s)
#pragma unroll
      for (int nt = 0; nt < 4; ++nt) {
        uint2 pk;
        pk.x = pk2(Sv[s * 4 + nt][0], Sv[s * 4 + nt][1]);
        pk.y = pk2(Sv[s * 4 + nt][2], Sv[s * 4 + nt][3]);
        *(uint2*)(ps + l16 * 140 + s * 64 + nt * 16 + quad * 4) = pk;
      }
#pragma unroll
    for (int ks = 0; ks < 4; ++ks) {
      short8 ap = *(short8*)(ps + l16 * 140 + ks * 32 + quad * 8);
#pragma unroll
      for (int nt = 0; nt < 3; ++nt) {
        const bf16s* vrow = vbase + (size_t)(nt * 16 + l16) * NPIX + key0 + ks * 32;
        short8 bv = *(const short8*)(vrow + quad * 8);
        O[nt] = __builtin_amdgcn_mfma_f32_16x16x32_bf16(ap, bv, O[nt], 0, 0, 0);
      }
    }
  }
#pragma unroll
  for (int r = 0; r < 4; ++r) {
    float lr = __shfl(l_run, quad * 4 + r, 64);
    float inv = 1.0f / lr;
    int qrow = q0 + quad * 4 + r;
    bf16s* orow = out + ((size_t)(b * 1024 + qrow)) * DIMC + h * HDIM;
#pragma unroll
    for (int nt = 0; nt < 3; ++nt) orow[nt * 16 + l16] = f2b(O[nt][r] * inv);
  }
}

extern "C" void kernel_launch(void* const* d_in, const int* in_sizes, int n_in,
                              void* d_out, int out_size, void* d_ws, size_t ws_size,
                              hipStream_t stream) {
  const float* x  = (const float*)d_in[0];
  const float* Wq = (const float*)d_in[1];
  const float* Wk = (const float*)d_in[2];
  const float* Wv = (const float*)d_in[3];
  const float* Wp = (const float*)d_in[4];
  const float* bp = (const float*)d_in[5];
  const float* sc = (const float*)d_in[6];
  const float* W1 = (const float*)d_in[7];
  const float* W2 = (const float*)d_in[8];
  float* ws = (float*)d_ws;
  const size_t S = (size_t)BB * NPIX * DIMC;  // 3,145,728
  float* qg   = ws;
  float* offs = ws + S;                  // 65,536
  float* pbuf = ws + S + 65536;          // 1,048,576
  bf16s* sb   = (bf16s*)(ws + S + 65536 + 1048576);
  bf16s* xh   = sb;                      // aliased as kbuf after Q GEMM
  bf16s* xl   = sb + S;                  // aliased as vbuf
  bf16s* qbuf = sb + 2 * S;
  bf16s* kvfb = sb + 3 * S;
  bf16s* wqh  = sb + 4 * S;
  bf16s* wql  = wqh + 147456;
  bf16s* wkb  = wql + 147456;
  bf16s* wvb  = wkb + 147456;
  bf16s* wpb  = wvb + 147456;
  bf16s* attnout = (bf16s*)qg;
  bf16s* kbuf = xh;
  bf16s* vbuf = xl;

  prep_weights<<<2304, 256, 0, stream>>>(Wq, Wk, Wv, Wp, wqh, wql, wkb, wvb, wpb);
  transpose_split<<<dim3(16, 6, BB), 256, 0, stream>>>(x, xh, xl);
  gemm_lds<0><<<dim3(6, 128), 256, 0, stream>>>(xh, xl, wqh, wql, qg, qbuf, nullptr, nullptr);
  conv_off_part<<<512, 256, 0, stream>>>(qg, W1, W2, pbuf);
  conv_off_reduce<<<256, 256, 0, stream>>>(pbuf, offs);
  bilinear_kernel<<<1024, 256, 0, stream>>>(x, offs, kvfb);
  gemm_lds<1><<<dim3(6, 128), 256, 0, stream>>>(kvfb, nullptr, wkb, wvb, nullptr, kbuf, vbuf, nullptr);
  flash_attn_kernel<<<1024, 256, 0, stream>>>(qbuf, kbuf, vbuf, sc, attnout);
  gemm_lds<2><<<dim3(6, 128), 256, 0, stream>>>(attnout, nullptr, wpb, nullptr, (float*)d_out, nullptr, nullptr, bp);
}